// Round 1
// baseline (117.196 us; speedup 1.0000x reference)
//
#include <hip/hip_runtime.h>

typedef __bf16 bf16x8 __attribute__((ext_vector_type(8)));
typedef float f32x4 __attribute__((ext_vector_type(4)));

#define MFMA16(a, b, c) __builtin_amdgcn_mfma_f32_16x16x32_bf16((a), (b), (c), 0, 0, 0)

// fp32 -> bf16 bits, round-to-nearest-even
static __device__ __forceinline__ unsigned short f2bf(float f) {
  unsigned int u = __float_as_uint(f);
  u += 0x7fffu + ((u >> 16) & 1u);
  return (unsigned short)(u >> 16);
}

// ---------------------------------------------------------------------------
// Kernel 0: W [1024][64] fp32 x3  ->  Wt bf16 [192][1024]  (Wq part * 0.125)
// ---------------------------------------------------------------------------
__global__ __launch_bounds__(256) void wt_kernel(
    const float* __restrict__ Wq, const float* __restrict__ Wk,
    const float* __restrict__ Wv, unsigned short* __restrict__ Wt) {
  int n = blockIdx.x;          // 0..191 output row (qkv col)
  int k0 = threadIdx.x * 4;    // 0..1023
  const float* W;
  int col;
  float scale;
  if (n < 64)       { W = Wq; col = n;       scale = 0.125f; }
  else if (n < 128) { W = Wk; col = n - 64;  scale = 1.0f; }
  else              { W = Wv; col = n - 128; scale = 1.0f; }
  ushort4 o;
  o.x = f2bf(W[(k0 + 0) * 64 + col] * scale);
  o.y = f2bf(W[(k0 + 1) * 64 + col] * scale);
  o.z = f2bf(W[(k0 + 2) * 64 + col] * scale);
  o.w = f2bf(W[(k0 + 3) * 64 + col] * scale);
  *reinterpret_cast<ushort4*>(&Wt[n * 1024 + k0]) = o;
}

// ---------------------------------------------------------------------------
// Kernel 1: QKV projection GEMM. M=16384 (b*s), K=1024, N=192.
//   Q (scaled) -> Qw [b][s][64] bf16 ; K -> Kw [b][s][64] ; V -> Vt [b][64][s]
// Block: 64 rows x 192 cols, 4 waves (each 16 rows x 192 cols).
// ---------------------------------------------------------------------------
__global__ __launch_bounds__(256) void qkv_kernel(
    const float* __restrict__ x, const unsigned short* __restrict__ Wt,
    const float* __restrict__ bq, const float* __restrict__ bk,
    const float* __restrict__ bv, unsigned short* __restrict__ Q,
    unsigned short* __restrict__ K, unsigned short* __restrict__ Vt) {
  __shared__ __align__(16) unsigned short xs[64][72];   // +8 pad
  __shared__ __align__(16) unsigned short ws[192][72];  // Wt tile [n][k]
  const int tid = threadIdx.x;
  const int w = tid >> 6, lane = tid & 63;
  const int lr = lane & 15, lg = lane >> 4;
  const int m0 = blockIdx.x * 64;

  f32x4 acc[12];
#pragma unroll
  for (int i = 0; i < 12; ++i)
#pragma unroll
    for (int j = 0; j < 4; ++j) acc[i][j] = 0.0f;

  for (int k0 = 0; k0 < 1024; k0 += 64) {
    __syncthreads();
    // stage x tile 64x64 fp32 -> bf16
#pragma unroll
    for (int it = 0; it < 4; ++it) {
      int slot = it * 256 + tid;
      int r = slot >> 4, c = (slot & 15) * 4;
      float4 v = *reinterpret_cast<const float4*>(&x[(m0 + r) * 1024 + k0 + c]);
      ushort4 o;
      o.x = f2bf(v.x); o.y = f2bf(v.y); o.z = f2bf(v.z); o.w = f2bf(v.w);
      *reinterpret_cast<ushort4*>(&xs[r][c]) = o;
    }
    // stage Wt tile 192x64 bf16
#pragma unroll
    for (int it = 0; it < 6; ++it) {
      int slot = it * 256 + tid;
      int r = slot >> 3, c = (slot & 7) * 8;
      *reinterpret_cast<uint4*>(&ws[r][c]) =
          *reinterpret_cast<const uint4*>(&Wt[r * 1024 + k0 + c]);
    }
    __syncthreads();

    bf16x8 a0 = *reinterpret_cast<const bf16x8*>(&xs[w * 16 + lr][lg * 8]);
    bf16x8 a1 = *reinterpret_cast<const bf16x8*>(&xs[w * 16 + lr][32 + lg * 8]);
#pragma unroll
    for (int nf = 0; nf < 12; ++nf) {
      bf16x8 b0 = *reinterpret_cast<const bf16x8*>(&ws[nf * 16 + lr][lg * 8]);
      bf16x8 b1 = *reinterpret_cast<const bf16x8*>(&ws[nf * 16 + lr][32 + lg * 8]);
      acc[nf] = MFMA16(a0, b0, acc[nf]);
      acc[nf] = MFMA16(a1, b1, acc[nf]);
    }
  }

  const int m_base = m0 + w * 16 + lg * 4;  // this lane's 4 output rows
  const int b = m0 >> 11;
  // Q columns (pre-scaled weights; bias needs same 0.125 scale)
#pragma unroll
  for (int nf = 0; nf < 4; ++nf) {
    int n = nf * 16 + lr;
    float bias = bq[n] * 0.125f;
#pragma unroll
    for (int i = 0; i < 4; ++i)
      Q[(m_base + i) * 64 + n] = f2bf(acc[nf][i] + bias);
  }
#pragma unroll
  for (int nf = 4; nf < 8; ++nf) {
    int n = (nf - 4) * 16 + lr;
    float bias = bk[n];
#pragma unroll
    for (int i = 0; i < 4; ++i)
      K[(m_base + i) * 64 + n] = f2bf(acc[nf][i] + bias);
  }
  // V stored transposed: Vt[b][d][s]
#pragma unroll
  for (int nf = 8; nf < 12; ++nf) {
    int d = (nf - 8) * 16 + lr;
    float bias = bv[d];
    ushort4 o;
    o.x = f2bf(acc[nf][0] + bias);
    o.y = f2bf(acc[nf][1] + bias);
    o.z = f2bf(acc[nf][2] + bias);
    o.w = f2bf(acc[nf][3] + bias);
    int s_local = m_base - (b << 11);
    *reinterpret_cast<ushort4*>(&Vt[((b * 64 + d) << 11) + s_local]) = o;
  }
}

// ---------------------------------------------------------------------------
// Kernel 2: flash attention. BQ=64 (4 waves x 16 q-rows), BKV=128, D=64.
// ---------------------------------------------------------------------------
__global__ __launch_bounds__(256) void attn_kernel(
    const unsigned short* __restrict__ Q, const unsigned short* __restrict__ K,
    const unsigned short* __restrict__ Vt, const int* __restrict__ mask,
    float* __restrict__ out) {
  __shared__ __align__(16) unsigned short qs[64][72];
  __shared__ __align__(16) unsigned short ks[128][72];
  __shared__ __align__(16) unsigned short vs[64][136];      // V^T tile [d][key]
  __shared__ __align__(16) unsigned short ps[4][16][136];   // per-wave P strip
  __shared__ float mAdd[128];

  const int b = blockIdx.y;
  const int q0 = blockIdx.x * 64;
  const int tid = threadIdx.x;
  const int w = tid >> 6, lane = tid & 63;
  const int lr = lane & 15, lg = lane >> 4;

  // stage Q tile once
#pragma unroll
  for (int it = 0; it < 2; ++it) {
    int slot = it * 256 + tid;
    int r = slot >> 3, c = (slot & 7) * 8;
    *reinterpret_cast<uint4*>(&qs[r][c]) =
        *reinterpret_cast<const uint4*>(&Q[(b * 2048 + q0 + r) * 64 + c]);
  }

  f32x4 oacc[4];
#pragma unroll
  for (int i = 0; i < 4; ++i)
#pragma unroll
    for (int j = 0; j < 4; ++j) oacc[i][j] = 0.0f;
  float m_i[4], l_i[4];
#pragma unroll
  for (int i = 0; i < 4; ++i) { m_i[i] = -__builtin_inff(); l_i[i] = 0.0f; }

  for (int kv0 = 0; kv0 < 2048; kv0 += 128) {
    __syncthreads();
#pragma unroll
    for (int it = 0; it < 4; ++it) {
      int slot = it * 256 + tid;
      int r = slot >> 3, c = (slot & 7) * 8;
      *reinterpret_cast<uint4*>(&ks[r][c]) =
          *reinterpret_cast<const uint4*>(&K[(b * 2048 + kv0 + r) * 64 + c]);
    }
#pragma unroll
    for (int it = 0; it < 4; ++it) {
      int slot = it * 256 + tid;
      int r = slot >> 4, c = (slot & 15) * 8;
      *reinterpret_cast<uint4*>(&vs[r][c]) =
          *reinterpret_cast<const uint4*>(&Vt[(b * 64 + r) * 2048 + kv0 + c]);
    }
    if (tid < 128) mAdd[tid] = mask[b * 2048 + kv0 + tid] ? 0.0f : -__builtin_inff();
    __syncthreads();

    // S strip [16 q x 128 keys] per wave (Q pre-scaled by 1/sqrt(D))
    bf16x8 a0 = *reinterpret_cast<const bf16x8*>(&qs[w * 16 + lr][lg * 8]);
    bf16x8 a1 = *reinterpret_cast<const bf16x8*>(&qs[w * 16 + lr][32 + lg * 8]);
    f32x4 sfr[8];
#pragma unroll
    for (int f = 0; f < 8; ++f) {
      bf16x8 kb0 = *reinterpret_cast<const bf16x8*>(&ks[f * 16 + lr][lg * 8]);
      bf16x8 kb1 = *reinterpret_cast<const bf16x8*>(&ks[f * 16 + lr][32 + lg * 8]);
      f32x4 s4;
#pragma unroll
      for (int j = 0; j < 4; ++j) s4[j] = 0.0f;
      s4 = MFMA16(a0, kb0, s4);
      s4 = MFMA16(a1, kb1, s4);
      float madd = mAdd[f * 16 + lr];
#pragma unroll
      for (int i = 0; i < 4; ++i) s4[i] += madd;
      sfr[f] = s4;
    }

    // online softmax: rows = lg*4+i, cols spread over lr (low 4 lane bits) + f
    float pm[4];
#pragma unroll
    for (int i = 0; i < 4; ++i) {
      float v = sfr[0][i];
#pragma unroll
      for (int f = 1; f < 8; ++f) v = fmaxf(v, sfr[f][i]);
      pm[i] = v;
    }
#pragma unroll
    for (int msk = 1; msk <= 8; msk <<= 1)
#pragma unroll
      for (int i = 0; i < 4; ++i)
        pm[i] = fmaxf(pm[i], __shfl_xor(pm[i], msk));

    float sc[4], rs[4];
#pragma unroll
    for (int i = 0; i < 4; ++i) {
      float nm = fmaxf(m_i[i], pm[i]);
      sc[i] = __expf(m_i[i] - nm);
      m_i[i] = nm;
      rs[i] = 0.0f;
    }
#pragma unroll
    for (int f = 0; f < 8; ++f)
#pragma unroll
      for (int i = 0; i < 4; ++i) {
        float p = __expf(sfr[f][i] - m_i[i]);
        sfr[f][i] = p;
        rs[i] += p;
      }
#pragma unroll
    for (int msk = 1; msk <= 8; msk <<= 1)
#pragma unroll
      for (int i = 0; i < 4; ++i) rs[i] += __shfl_xor(rs[i], msk);
#pragma unroll
    for (int i = 0; i < 4; ++i) l_i[i] = l_i[i] * sc[i] + rs[i];
#pragma unroll
    for (int nf = 0; nf < 4; ++nf)
#pragma unroll
      for (int i = 0; i < 4; ++i) oacc[nf][i] *= sc[i];

    // P strip -> LDS (bf16), then PV MFMA (A from ps, B from vs rows)
#pragma unroll
    for (int f = 0; f < 8; ++f)
#pragma unroll
      for (int i = 0; i < 4; ++i)
        ps[w][lg * 4 + i][f * 16 + lr] = f2bf(sfr[f][i]);

    bf16x8 pa[4];
#pragma unroll
    for (int k2 = 0; k2 < 4; ++k2)
      pa[k2] = *reinterpret_cast<const bf16x8*>(&ps[w][lr][k2 * 32 + lg * 8]);
#pragma unroll
    for (int nf = 0; nf < 4; ++nf)
#pragma unroll
      for (int k2 = 0; k2 < 4; ++k2) {
        bf16x8 vb = *reinterpret_cast<const bf16x8*>(&vs[nf * 16 + lr][k2 * 32 + lg * 8]);
        oacc[nf] = MFMA16(pa[k2], vb, oacc[nf]);
      }
  }

#pragma unroll
  for (int nf = 0; nf < 4; ++nf) {
    int d = nf * 16 + lr;
#pragma unroll
    for (int i = 0; i < 4; ++i) {
      int q = q0 + w * 16 + lg * 4 + i;
      out[(b * 2048 + q) * 64 + d] = oacc[nf][i] / l_i[i];
    }
  }
}

// ---------------------------------------------------------------------------
extern "C" void kernel_launch(void* const* d_in, const int* in_sizes, int n_in,
                              void* d_out, int out_size, void* d_ws, size_t ws_size,
                              hipStream_t stream) {
  const float* x  = (const float*)d_in[0];
  const int* mask = (const int*)d_in[1];
  const float* Wq = (const float*)d_in[2];
  const float* bq = (const float*)d_in[3];
  const float* Wk = (const float*)d_in[4];
  const float* bk = (const float*)d_in[5];
  const float* Wv = (const float*)d_in[6];
  const float* bv = (const float*)d_in[7];
  float* out = (float*)d_out;

  unsigned short* Wt = (unsigned short*)d_ws;       // [192][1024]
  unsigned short* Qw = Wt + 192 * 1024;             // [8][2048][64]
  unsigned short* Kw = Qw + 8 * 2048 * 64;          // [8][2048][64]
  unsigned short* Vt = Kw + 8 * 2048 * 64;          // [8][64][2048]

  hipLaunchKernelGGL(wt_kernel, dim3(192), dim3(256), 0, stream, Wq, Wk, Wv, Wt);
  hipLaunchKernelGGL(qkv_kernel, dim3(256), dim3(256), 0, stream,
                     x, Wt, bq, bk, bv, Qw, Kw, Vt);
  hipLaunchKernelGGL(attn_kernel, dim3(32, 8), dim3(256), 0, stream,
                     Qw, Kw, Vt, mask, out);
}

// Round 2
// 70.030 us; speedup vs baseline: 1.6735x; 1.6735x over previous
//
#include <hip/hip_runtime.h>

typedef __bf16 bf16x8 __attribute__((ext_vector_type(8)));
typedef float f32x4 __attribute__((ext_vector_type(4)));
typedef unsigned short u16x8 __attribute__((ext_vector_type(8)));

#define MFMA16(a, b, c) __builtin_amdgcn_mfma_f32_16x16x32_bf16((a), (b), (c), 0, 0, 0)

// fp32 -> bf16 bits, round-to-nearest-even
static __device__ __forceinline__ unsigned short f2bf(float f) {
  unsigned int u = __float_as_uint(f);
  u += 0x7fffu + ((u >> 16) & 1u);
  return (unsigned short)(u >> 16);
}

// async global->LDS, 16B per lane. LDS dest is wave-uniform base + lane*16.
static __device__ __forceinline__ void gld_lds16(const void* g, void* l) {
  __builtin_amdgcn_global_load_lds(
      (const __attribute__((address_space(1))) unsigned int*)(g),
      (__attribute__((address_space(3))) unsigned int*)(l), 16, 0, 0);
}

// ---------------------------------------------------------------------------
// Kernel 0: W [1024][64] fp32 x3 -> Wt bf16 [192][1024], PRE-SWIZZLED so that
// a linear global_load_lds of any 64-col tile yields chunk j of row n holding
// logical chunk j^(n&7)  (16B chunks within each 128B row). Wq part * 0.125.
// ---------------------------------------------------------------------------
__global__ __launch_bounds__(128) void wt_kernel(
    const float* __restrict__ Wq, const float* __restrict__ Wk,
    const float* __restrict__ Wv, unsigned short* __restrict__ Wt) {
  const int n = blockIdx.x;       // 0..191 (qkv output col)
  const int jl = threadIdx.x;     // 0..127 logical 8-elem chunk of K
  const float* W;
  int col;
  float scale;
  if (n < 64)       { W = Wq; col = n;       scale = 0.125f; }
  else if (n < 128) { W = Wk; col = n - 64;  scale = 1.0f; }
  else              { W = Wv; col = n - 128; scale = 1.0f; }
  const int js = (jl & ~7) | ((jl & 7) ^ (n & 7));  // swizzled chunk position
  u16x8 o;
#pragma unroll
  for (int e = 0; e < 8; ++e) o[e] = f2bf(W[(jl * 8 + e) * 64 + col] * scale);
  *reinterpret_cast<u16x8*>(&Wt[n * 1024 + js * 8]) = o;
}

// ---------------------------------------------------------------------------
// Kernel 1: QKV projection GEMM. M=16384, K=1024, N=192.
// Tile 32x192, grid 512, 512 threads (8 waves: 2 row-groups x 4 col-groups).
// x staged as raw fp32 via global_load_lds (source-swizzled), converted to
// bf16 at fragment read. Wt staged via global_load_lds (pre-swizzled global).
// ---------------------------------------------------------------------------
__global__ __launch_bounds__(512, 4) void qkv_kernel(
    const float* __restrict__ x, const unsigned short* __restrict__ Wt,
    const float* __restrict__ bq, const float* __restrict__ bk,
    const float* __restrict__ bv, unsigned short* __restrict__ Q,
    unsigned short* __restrict__ K, unsigned short* __restrict__ Vt) {
  __shared__ __align__(16) float xs[32 * 64];            // 8 KB, swizzled content
  __shared__ __align__(16) unsigned short ws[192 * 64];  // 24 KB, swizzled content
  const int tid = threadIdx.x;
  const int w = tid >> 6, lane = tid & 63;
  const int lr = lane & 15, lg = lane >> 4;
  const int wg = w >> 2, wc = w & 3;   // row-group (0/1), col-group (0..3)
  const int m0 = blockIdx.x * 32;

  // staging addresses
  const int xrow = tid >> 4, xchk = tid & 15;
  const float* xsrc = x + (m0 + xrow) * 1024 + ((xchk ^ ((xrow & 7) << 1)) * 4);
  char* xdst = (char*)xs + w * 1024;
  const unsigned short* wsrc0 = Wt + ((0 * 512 + tid) >> 3) * 1024 + (tid & 7) * 8;
  const unsigned short* wsrc1 = Wt + ((1 * 512 + tid) >> 3) * 1024 + (tid & 7) * 8;
  const unsigned short* wsrc2 = Wt + ((2 * 512 + tid) >> 3) * 1024 + (tid & 7) * 8;
  char* wdst0 = (char*)ws + 0 * 8192 + w * 1024;
  char* wdst1 = (char*)ws + 1 * 8192 + w * 1024;
  char* wdst2 = (char*)ws + 2 * 8192 + w * 1024;

  f32x4 acc[3] = {};
  const int arow = wg * 16 + lr;
  const float* xrd = xs + arow * 64;
  const int axor = (lr & 7) << 1;

  for (int k0 = 0; k0 < 1024; k0 += 64) {
    __syncthreads();  // previous iteration's compute done
    gld_lds16(xsrc + k0, xdst);
    gld_lds16(wsrc0 + k0, wdst0);
    gld_lds16(wsrc1 + k0, wdst1);
    gld_lds16(wsrc2 + k0, wdst2);
    __syncthreads();  // drains vmcnt(0): tiles ready

    bf16x8 a[2];
#pragma unroll
    for (int kh = 0; kh < 2; ++kh) {
      const int sc = (kh * 8 + lg * 2) ^ axor;
      f32x4 v0 = *reinterpret_cast<const f32x4*>(xrd + sc * 4);
      f32x4 v1 = *reinterpret_cast<const f32x4*>(xrd + sc * 4 + 4);
      union { u16x8 u; bf16x8 b; } cv;
#pragma unroll
      for (int j = 0; j < 4; ++j) { cv.u[j] = f2bf(v0[j]); cv.u[4 + j] = f2bf(v1[j]); }
      a[kh] = cv.b;
    }
#pragma unroll
    for (int cf = 0; cf < 3; ++cf) {
      const int n = wc * 48 + cf * 16 + lr;
      const unsigned short* wr = ws + n * 64;
#pragma unroll
      for (int kh = 0; kh < 2; ++kh) {
        const int sc = (kh * 4 + lg) ^ (n & 7);
        bf16x8 bv8 = *reinterpret_cast<const bf16x8*>(wr + sc * 8);
        acc[cf] = MFMA16(a[kh], bv8, acc[cf]);
      }
    }
  }

  const int mb = m0 + wg * 16 + lg * 4;  // first of this lane's 4 output rows
  const int b = m0 >> 11;
#pragma unroll
  for (int cf = 0; cf < 3; ++cf) {
    const int n = wc * 48 + cf * 16 + lr;
    if (n < 64) {
      const float bias = bq[n] * 0.125f;
#pragma unroll
      for (int i = 0; i < 4; ++i) Q[(mb + i) * 64 + n] = f2bf(acc[cf][i] + bias);
    } else if (n < 128) {
      const int nn = n - 64;
      const float bias = bk[nn];
#pragma unroll
      for (int i = 0; i < 4; ++i) K[(mb + i) * 64 + nn] = f2bf(acc[cf][i] + bias);
    } else {
      const int d = n - 128;
      const float bias = bv[d];
      ushort4 o;
      o.x = f2bf(acc[cf][0] + bias);
      o.y = f2bf(acc[cf][1] + bias);
      o.z = f2bf(acc[cf][2] + bias);
      o.w = f2bf(acc[cf][3] + bias);
      const int sl = (m0 & 2047) + wg * 16 + lg * 4;
      *reinterpret_cast<ushort4*>(&Vt[((b * 64 + d) << 11) + sl]) = o;
    }
  }
}

// ---------------------------------------------------------------------------
// Kernel 2: flash attention PARTIAL over a 512-key chunk. BQ=64 (4 waves x 16
// rows), BKV=64. grid (32 qtiles, 8 batch, 4 chunks) = 1024 blocks, LDS 37 KB
// -> 4 blocks/CU. Emits unnormalized O plus (m, l) per row for the merge.
// ---------------------------------------------------------------------------
__global__ __launch_bounds__(256, 4) void attn_kernel(
    const unsigned short* __restrict__ Q, const unsigned short* __restrict__ K,
    const unsigned short* __restrict__ Vt, const int* __restrict__ mask,
    float* __restrict__ Op, float* __restrict__ mp, float* __restrict__ lp) {
  __shared__ __align__(16) unsigned short qs[64][72];
  __shared__ __align__(16) unsigned short ks[64][72];
  __shared__ __align__(16) unsigned short vs[64][72];   // V^T tile [d][key]
  __shared__ __align__(16) unsigned short ps[4][16][72];
  __shared__ float mAdd[64];

  const int b = blockIdx.y, c = blockIdx.z;
  const int q0 = blockIdx.x * 64;
  const int tid = threadIdx.x;
  const int w = tid >> 6, lane = tid & 63;
  const int lr = lane & 15, lg = lane >> 4;

#pragma unroll
  for (int it = 0; it < 2; ++it) {
    const int slot = it * 256 + tid;
    const int r = slot >> 3, cc = (slot & 7) * 8;
    *reinterpret_cast<uint4*>(&qs[r][cc]) =
        *reinterpret_cast<const uint4*>(&Q[(b * 2048 + q0 + r) * 64 + cc]);
  }

  f32x4 oacc[4] = {};
  float m_i[4], l_i[4];
#pragma unroll
  for (int i = 0; i < 4; ++i) { m_i[i] = -__builtin_inff(); l_i[i] = 0.0f; }

  for (int it = 0; it < 8; ++it) {
    const int kv0 = c * 512 + it * 64;
    __syncthreads();
#pragma unroll
    for (int s2 = 0; s2 < 2; ++s2) {
      const int slot = s2 * 256 + tid;
      const int r = slot >> 3, cc = (slot & 7) * 8;
      *reinterpret_cast<uint4*>(&ks[r][cc]) =
          *reinterpret_cast<const uint4*>(&K[(b * 2048 + kv0 + r) * 64 + cc]);
      *reinterpret_cast<uint4*>(&vs[r][cc]) =
          *reinterpret_cast<const uint4*>(&Vt[(b * 64 + r) * 2048 + kv0 + cc]);
    }
    if (tid < 64) mAdd[tid] = mask[b * 2048 + kv0 + tid] ? 0.0f : -__builtin_inff();
    __syncthreads();

    bf16x8 a0 = *reinterpret_cast<const bf16x8*>(&qs[w * 16 + lr][lg * 8]);
    bf16x8 a1 = *reinterpret_cast<const bf16x8*>(&qs[w * 16 + lr][32 + lg * 8]);
    f32x4 sfr[4];
#pragma unroll
    for (int f = 0; f < 4; ++f) {
      bf16x8 kb0 = *reinterpret_cast<const bf16x8*>(&ks[f * 16 + lr][lg * 8]);
      bf16x8 kb1 = *reinterpret_cast<const bf16x8*>(&ks[f * 16 + lr][32 + lg * 8]);
      f32x4 s4 = {};
      s4 = MFMA16(a0, kb0, s4);
      s4 = MFMA16(a1, kb1, s4);
      const float madd = mAdd[f * 16 + lr];
#pragma unroll
      for (int i = 0; i < 4; ++i) s4[i] += madd;
      sfr[f] = s4;
    }

    float pm[4];
#pragma unroll
    for (int i = 0; i < 4; ++i)
      pm[i] = fmaxf(fmaxf(sfr[0][i], sfr[1][i]), fmaxf(sfr[2][i], sfr[3][i]));
#pragma unroll
    for (int msk = 1; msk <= 8; msk <<= 1)
#pragma unroll
      for (int i = 0; i < 4; ++i) pm[i] = fmaxf(pm[i], __shfl_xor(pm[i], msk));

    float sc[4], rs[4];
#pragma unroll
    for (int i = 0; i < 4; ++i) {
      const float nm = fmaxf(m_i[i], pm[i]);
      sc[i] = __expf(m_i[i] - nm);
      m_i[i] = nm;
      rs[i] = 0.0f;
    }
#pragma unroll
    for (int f = 0; f < 4; ++f)
#pragma unroll
      for (int i = 0; i < 4; ++i) {
        const float p = __expf(sfr[f][i] - m_i[i]);
        sfr[f][i] = p;
        rs[i] += p;
      }
#pragma unroll
    for (int msk = 1; msk <= 8; msk <<= 1)
#pragma unroll
      for (int i = 0; i < 4; ++i) rs[i] += __shfl_xor(rs[i], msk);
#pragma unroll
    for (int i = 0; i < 4; ++i) l_i[i] = l_i[i] * sc[i] + rs[i];
#pragma unroll
    for (int nf = 0; nf < 4; ++nf)
#pragma unroll
      for (int i = 0; i < 4; ++i) oacc[nf][i] *= sc[i];

#pragma unroll
    for (int f = 0; f < 4; ++f)
#pragma unroll
      for (int i = 0; i < 4; ++i)
        ps[w][lg * 4 + i][f * 16 + lr] = f2bf(sfr[f][i]);

    bf16x8 pa[2];
#pragma unroll
    for (int k2 = 0; k2 < 2; ++k2)
      pa[k2] = *reinterpret_cast<const bf16x8*>(&ps[w][lr][k2 * 32 + lg * 8]);
#pragma unroll
    for (int nf = 0; nf < 4; ++nf)
#pragma unroll
      for (int k2 = 0; k2 < 2; ++k2) {
        bf16x8 vb = *reinterpret_cast<const bf16x8*>(&vs[nf * 16 + lr][k2 * 32 + lg * 8]);
        oacc[nf] = MFMA16(pa[k2], vb, oacc[nf]);
      }
  }

  const int growb = b * 2048 + q0 + w * 16 + lg * 4;  // global row of i=0
#pragma unroll
  for (int nf = 0; nf < 4; ++nf) {
    const int d = nf * 16 + lr;
#pragma unroll
    for (int i = 0; i < 4; ++i)
      Op[(c * 16384 + growb + i) * 64 + d] = oacc[nf][i];
  }
  if (lr == 0) {
#pragma unroll
    for (int i = 0; i < 4; ++i) {
      mp[c * 16384 + growb + i] = m_i[i];
      lp[c * 16384 + growb + i] = l_i[i];
    }
  }
}

// ---------------------------------------------------------------------------
// Kernel 3: merge the 4 kv-chunk partials. out = sum(w_c*O_c)/sum(w_c*l_c).
// ---------------------------------------------------------------------------
__global__ __launch_bounds__(256) void merge_kernel(
    const float* __restrict__ Op, const float* __restrict__ mp,
    const float* __restrict__ lp, float* __restrict__ out) {
  const int t = blockIdx.x * 256 + threadIdx.x;  // 0..262143
  const int row = t >> 4;                        // b*2048 + q
  const int cc = (t & 15) * 4;
  float mv[4], lv[4];
#pragma unroll
  for (int c = 0; c < 4; ++c) {
    mv[c] = mp[c * 16384 + row];
    lv[c] = lp[c * 16384 + row];
  }
  const float M = fmaxf(fmaxf(mv[0], mv[1]), fmaxf(mv[2], mv[3]));
  float L = 0.0f;
  f32x4 o = {};
#pragma unroll
  for (int c = 0; c < 4; ++c) {
    const float wc = __expf(mv[c] - M);
    L += wc * lv[c];
    f32x4 oc = *reinterpret_cast<const f32x4*>(&Op[(c * 16384 + row) * 64 + cc]);
    o += oc * wc;
  }
  const float inv = 1.0f / L;
  *reinterpret_cast<f32x4*>(&out[row * 64 + cc]) = o * inv;
}

// ---------------------------------------------------------------------------
extern "C" void kernel_launch(void* const* d_in, const int* in_sizes, int n_in,
                              void* d_out, int out_size, void* d_ws, size_t ws_size,
                              hipStream_t stream) {
  const float* x  = (const float*)d_in[0];
  const int* mask = (const int*)d_in[1];
  const float* Wq = (const float*)d_in[2];
  const float* bq = (const float*)d_in[3];
  const float* Wk = (const float*)d_in[4];
  const float* bk = (const float*)d_in[5];
  const float* Wv = (const float*)d_in[6];
  const float* bv = (const float*)d_in[7];
  float* out = (float*)d_out;

  unsigned short* Wt = (unsigned short*)d_ws;   // [192][1024] swizzled bf16
  unsigned short* Qw = Wt + 192 * 1024;         // [8][2048][64]
  unsigned short* Kw = Qw + 16384 * 64;         // [8][2048][64]
  unsigned short* Vt = Kw + 16384 * 64;         // [8][64][2048]
  float* Op = (float*)(Vt + 16384 * 64);        // [4][16384][64]
  float* mp = Op + 4 * 16384 * 64;              // [4][16384]
  float* lp = mp + 4 * 16384;                   // [4][16384]

  hipLaunchKernelGGL(wt_kernel, dim3(192), dim3(128), 0, stream, Wq, Wk, Wv, Wt);
  hipLaunchKernelGGL(qkv_kernel, dim3(512), dim3(512), 0, stream,
                     x, Wt, bq, bk, bv, Qw, Kw, Vt);
  hipLaunchKernelGGL(attn_kernel, dim3(32, 8, 4), dim3(256), 0, stream,
                     Qw, Kw, Vt, mask, Op, mp, lp);
  hipLaunchKernelGGL(merge_kernel, dim3(1024), dim3(256), 0, stream,
                     Op, mp, lp, out);
}

// Round 3
// 66.178 us; speedup vs baseline: 1.7709x; 1.0582x over previous
//
#include <hip/hip_runtime.h>

typedef __bf16 bf16x8 __attribute__((ext_vector_type(8)));
typedef float f32x4 __attribute__((ext_vector_type(4)));
typedef unsigned short u16x8 __attribute__((ext_vector_type(8)));

#define MFMA16(a, b, c) __builtin_amdgcn_mfma_f32_16x16x32_bf16((a), (b), (c), 0, 0, 0)

// fp32 -> bf16 bits, round-to-nearest-even
static __device__ __forceinline__ unsigned short f2bf(float f) {
  unsigned int u = __float_as_uint(f);
  u += 0x7fffu + ((u >> 16) & 1u);
  return (unsigned short)(u >> 16);
}

// async global->LDS, 16B per lane. LDS dest is wave-uniform base + lane*16.
static __device__ __forceinline__ void gld_lds16(const void* g, void* l) {
  __builtin_amdgcn_global_load_lds(
      (const __attribute__((address_space(1))) unsigned int*)(g),
      (__attribute__((address_space(3))) unsigned int*)(l), 16, 0, 0);
}

// ---------------------------------------------------------------------------
// Kernel 0: W [1024][64] fp32 x3 -> Wt bf16 [192][1024], PRE-SWIZZLED so that
// a linear global_load_lds of any 64-col tile yields chunk j of row n holding
// logical chunk j^(n&7)  (16B chunks within each 128B row). Wq part * 0.125.
// ---------------------------------------------------------------------------
__global__ __launch_bounds__(128) void wt_kernel(
    const float* __restrict__ Wq, const float* __restrict__ Wk,
    const float* __restrict__ Wv, unsigned short* __restrict__ Wt) {
  const int n = blockIdx.x;       // 0..191 (qkv output col)
  const int jl = threadIdx.x;     // 0..127 logical 8-elem chunk of K
  const float* W;
  int col;
  float scale;
  if (n < 64)       { W = Wq; col = n;       scale = 0.125f; }
  else if (n < 128) { W = Wk; col = n - 64;  scale = 1.0f; }
  else              { W = Wv; col = n - 128; scale = 1.0f; }
  const int js = (jl & ~7) | ((jl & 7) ^ (n & 7));  // swizzled chunk position
  u16x8 o;
#pragma unroll
  for (int e = 0; e < 8; ++e) o[e] = f2bf(W[(jl * 8 + e) * 64 + col] * scale);
  *reinterpret_cast<u16x8*>(&Wt[n * 1024 + js * 8]) = o;
}

// ---------------------------------------------------------------------------
// Kernel 1: QKV projection GEMM. M=16384, K=1024, N=192.
// Tile 32x192, grid 512, 512 threads (8 waves). Double-buffered LDS (64 KB),
// 2-phase: stage(t+1) issued before compute(t), ONE barrier per k-step whose
// vmcnt(0) drain lands after the stage overlapped the whole compute phase.
// ---------------------------------------------------------------------------
__global__ __launch_bounds__(512, 2) void qkv_kernel(
    const float* __restrict__ x, const unsigned short* __restrict__ Wt,
    const float* __restrict__ bq, const float* __restrict__ bk,
    const float* __restrict__ bv, unsigned short* __restrict__ Q,
    unsigned short* __restrict__ K, unsigned short* __restrict__ Vt) {
  __shared__ __align__(16) float xs[2][32 * 64];            // 2 x 8 KB
  __shared__ __align__(16) unsigned short ws[2][192 * 64];  // 2 x 24 KB
  const int tid = threadIdx.x;
  const int w = tid >> 6, lane = tid & 63;
  const int lr = lane & 15, lg = lane >> 4;
  const int wg = w >> 2, wc = w & 3;   // row-group (0/1), col-group (0..3)
  const int m0 = blockIdx.x * 32;

  // staging addresses (source-swizzled; LDS dest linear per rule 21)
  const int xrow = tid >> 4, xchk = tid & 15;
  const float* xsrc = x + (m0 + xrow) * 1024 + ((xchk ^ ((xrow & 7) << 1)) * 4);
  const unsigned short* wsrc0 = Wt + ((0 * 512 + tid) >> 3) * 1024 + (tid & 7) * 8;
  const unsigned short* wsrc1 = Wt + ((1 * 512 + tid) >> 3) * 1024 + (tid & 7) * 8;
  const unsigned short* wsrc2 = Wt + ((2 * 512 + tid) >> 3) * 1024 + (tid & 7) * 8;

  f32x4 acc[3] = {};
  const int arow = wg * 16 + lr;
  const int axor = (lr & 7) << 1;

#define QKV_STAGE(k0, buf)                                              \
  do {                                                                  \
    gld_lds16(xsrc + (k0), (char*)(&xs[buf][0]) + w * 1024);            \
    gld_lds16(wsrc0 + (k0), (char*)(&ws[buf][0]) + w * 1024);           \
    gld_lds16(wsrc1 + (k0), (char*)(&ws[buf][0]) + 8192 + w * 1024);    \
    gld_lds16(wsrc2 + (k0), (char*)(&ws[buf][0]) + 16384 + w * 1024);   \
  } while (0)

  QKV_STAGE(0, 0);
  __syncthreads();
  int cur = 0;
#pragma unroll 2
  for (int t = 0; t < 16; ++t) {
    if (t < 15) QKV_STAGE((t + 1) * 64, cur ^ 1);

    const float* xrd = &xs[cur][arow * 64];
    const unsigned short* wsb = &ws[cur][0];
    bf16x8 a[2];
#pragma unroll
    for (int kh = 0; kh < 2; ++kh) {
      const int sc = (kh * 8 + lg * 2) ^ axor;
      f32x4 v0 = *reinterpret_cast<const f32x4*>(xrd + sc * 4);
      f32x4 v1 = *reinterpret_cast<const f32x4*>(xrd + sc * 4 + 4);
      union { u16x8 u; bf16x8 b; } cv;
#pragma unroll
      for (int j = 0; j < 4; ++j) { cv.u[j] = f2bf(v0[j]); cv.u[4 + j] = f2bf(v1[j]); }
      a[kh] = cv.b;
    }
#pragma unroll
    for (int cf = 0; cf < 3; ++cf) {
      const int n = wc * 48 + cf * 16 + lr;
      const unsigned short* wr = wsb + n * 64;
#pragma unroll
      for (int kh = 0; kh < 2; ++kh) {
        const int sc = (kh * 4 + lg) ^ (n & 7);
        bf16x8 bv8 = *reinterpret_cast<const bf16x8*>(wr + sc * 8);
        acc[cf] = MFMA16(a[kh], bv8, acc[cf]);
      }
    }
    __syncthreads();  // drains vmcnt(0): stage(t+1) complete; cur free to reuse
    cur ^= 1;
  }
#undef QKV_STAGE

  const int mb = m0 + wg * 16 + lg * 4;  // first of this lane's 4 output rows
  const int b = m0 >> 11;
#pragma unroll
  for (int cf = 0; cf < 3; ++cf) {
    const int n = wc * 48 + cf * 16 + lr;
    if (n < 64) {
      const float bias = bq[n] * 0.125f;
#pragma unroll
      for (int i = 0; i < 4; ++i) Q[(mb + i) * 64 + n] = f2bf(acc[cf][i] + bias);
    } else if (n < 128) {
      const int nn = n - 64;
      const float bias = bk[nn];
#pragma unroll
      for (int i = 0; i < 4; ++i) K[(mb + i) * 64 + nn] = f2bf(acc[cf][i] + bias);
    } else {
      const int d = n - 128;
      const float bias = bv[d];
      ushort4 o;
      o.x = f2bf(acc[cf][0] + bias);
      o.y = f2bf(acc[cf][1] + bias);
      o.z = f2bf(acc[cf][2] + bias);
      o.w = f2bf(acc[cf][3] + bias);
      const int sl = (m0 & 2047) + wg * 16 + lg * 4;
      *reinterpret_cast<ushort4*>(&Vt[((b * 64 + d) << 11) + sl]) = o;
    }
  }
}

// ---------------------------------------------------------------------------
// Kernel 2: flash attention PARTIAL over a 512-key chunk. BQ=64 (4 waves x 16
// rows), BKV=64, 4 blocks/CU. T14 async-STAGE: registers hold tile t+1 while
// LDS holds tile t; raw s_barrier + lgkmcnt(0) so global loads stay in flight.
// ---------------------------------------------------------------------------
__global__ __launch_bounds__(256, 4) void attn_kernel(
    const unsigned short* __restrict__ Q, const unsigned short* __restrict__ K,
    const unsigned short* __restrict__ Vt, const int* __restrict__ mask,
    float* __restrict__ Op, float* __restrict__ mp, float* __restrict__ lp) {
  __shared__ __align__(16) unsigned short qs[64][72];
  __shared__ __align__(16) unsigned short ks[64][72];
  __shared__ __align__(16) unsigned short vs[64][72];   // V^T tile [d][key]
  __shared__ __align__(16) unsigned short ps[4][16][72];
  __shared__ float mAdd[64];

  const int b = blockIdx.y, c = blockIdx.z;
  const int q0 = blockIdx.x * 64;
  const int tid = threadIdx.x;
  const int w = tid >> 6, lane = tid & 63;
  const int lr = lane & 15, lg = lane >> 4;
  const int sr = tid >> 3, scc = (tid & 7) * 8;  // staging row/col (per s2=0)

  // ---- stage Q tile once ----
#pragma unroll
  for (int it = 0; it < 2; ++it) {
    const int slot = it * 256 + tid;
    const int r = slot >> 3, cc = (slot & 7) * 8;
    *reinterpret_cast<uint4*>(&qs[r][cc]) =
        *reinterpret_cast<const uint4*>(&Q[(b * 2048 + q0 + r) * 64 + cc]);
  }

  // tile-0 loads into registers (overlap with Q staging barrier)
  uint4 rk0, rk1, rv0, rv1;
  float rm;
  {
    const int kv0 = c * 512;
    rk0 = *reinterpret_cast<const uint4*>(&K[(b * 2048 + kv0 + sr) * 64 + scc]);
    rv0 = *reinterpret_cast<const uint4*>(&Vt[(b * 64 + sr) * 2048 + kv0 + scc]);
    rk1 = *reinterpret_cast<const uint4*>(&K[(b * 2048 + kv0 + 32 + sr) * 64 + scc]);
    rv1 = *reinterpret_cast<const uint4*>(&Vt[(b * 64 + 32 + sr) * 2048 + kv0 + scc]);
    rm = 0.0f;
    if (tid < 64) rm = mask[b * 2048 + kv0 + tid] ? 0.0f : -__builtin_inff();
  }
  __syncthreads();  // qs visible

  // hoist Q fragments (constant over the KV loop)
  const bf16x8 a0 = *reinterpret_cast<const bf16x8*>(&qs[w * 16 + lr][lg * 8]);
  const bf16x8 a1 = *reinterpret_cast<const bf16x8*>(&qs[w * 16 + lr][32 + lg * 8]);

  f32x4 oacc[4] = {};
  float m_i[4], l_i[4];
#pragma unroll
  for (int i = 0; i < 4; ++i) { m_i[i] = -__builtin_inff(); l_i[i] = 0.0f; }

  for (int it = 0; it < 8; ++it) {
    // all waves done READING LDS tiles of it-1 (their ds_reads were consumed
    // by MFMAs -> lgkmcnt already drained); raw barrier keeps vmcnt in flight
    __builtin_amdgcn_s_barrier();

    // write tile `it` from registers to LDS (compiler inserts the vmcnt wait)
    *reinterpret_cast<uint4*>(&ks[sr][scc]) = rk0;
    *reinterpret_cast<uint4*>(&vs[sr][scc]) = rv0;
    *reinterpret_cast<uint4*>(&ks[32 + sr][scc]) = rk1;
    *reinterpret_cast<uint4*>(&vs[32 + sr][scc]) = rv1;
    if (tid < 64) mAdd[tid] = rm;

    // issue tile it+1 loads; they fly during barrier + compute below
    if (it < 7) {
      const int kv0 = c * 512 + (it + 1) * 64;
      rk0 = *reinterpret_cast<const uint4*>(&K[(b * 2048 + kv0 + sr) * 64 + scc]);
      rv0 = *reinterpret_cast<const uint4*>(&Vt[(b * 64 + sr) * 2048 + kv0 + scc]);
      rk1 = *reinterpret_cast<const uint4*>(&K[(b * 2048 + kv0 + 32 + sr) * 64 + scc]);
      rv1 = *reinterpret_cast<const uint4*>(&Vt[(b * 64 + 32 + sr) * 2048 + kv0 + scc]);
      rm = 0.0f;
      if (tid < 64) rm = mask[b * 2048 + kv0 + tid] ? 0.0f : -__builtin_inff();
    }

    asm volatile("s_waitcnt lgkmcnt(0)" ::: "memory");  // my ds_writes done
    __builtin_amdgcn_s_barrier();                       // everyone's done

    // ---- QK^T ----
    f32x4 sfr[4];
#pragma unroll
    for (int f = 0; f < 4; ++f) {
      bf16x8 kb0 = *reinterpret_cast<const bf16x8*>(&ks[f * 16 + lr][lg * 8]);
      bf16x8 kb1 = *reinterpret_cast<const bf16x8*>(&ks[f * 16 + lr][32 + lg * 8]);
      f32x4 s4 = {};
      s4 = MFMA16(a0, kb0, s4);
      s4 = MFMA16(a1, kb1, s4);
      const float madd = mAdd[f * 16 + lr];
#pragma unroll
      for (int i = 0; i < 4; ++i) s4[i] += madd;
      sfr[f] = s4;
    }

    // ---- online softmax (rows = lg*4+i; cols spread over lr + f) ----
    float pm[4];
#pragma unroll
    for (int i = 0; i < 4; ++i)
      pm[i] = fmaxf(fmaxf(sfr[0][i], sfr[1][i]), fmaxf(sfr[2][i], sfr[3][i]));
#pragma unroll
    for (int msk = 1; msk <= 8; msk <<= 1)
#pragma unroll
      for (int i = 0; i < 4; ++i) pm[i] = fmaxf(pm[i], __shfl_xor(pm[i], msk));

    float sc[4], rs[4];
#pragma unroll
    for (int i = 0; i < 4; ++i) {
      const float nm = fmaxf(m_i[i], pm[i]);
      sc[i] = __expf(m_i[i] - nm);
      m_i[i] = nm;
      rs[i] = 0.0f;
    }
#pragma unroll
    for (int f = 0; f < 4; ++f)
#pragma unroll
      for (int i = 0; i < 4; ++i) {
        const float p = __expf(sfr[f][i] - m_i[i]);
        sfr[f][i] = p;
        rs[i] += p;
      }
#pragma unroll
    for (int msk = 1; msk <= 8; msk <<= 1)
#pragma unroll
      for (int i = 0; i < 4; ++i) rs[i] += __shfl_xor(rs[i], msk);
#pragma unroll
    for (int i = 0; i < 4; ++i) l_i[i] = l_i[i] * sc[i] + rs[i];
#pragma unroll
    for (int nf = 0; nf < 4; ++nf)
#pragma unroll
      for (int i = 0; i < 4; ++i) oacc[nf][i] *= sc[i];

    // ---- P -> LDS (per-wave strip, no barrier needed) ----
#pragma unroll
    for (int f = 0; f < 4; ++f)
#pragma unroll
      for (int i = 0; i < 4; ++i)
        ps[w][lg * 4 + i][f * 16 + lr] = f2bf(sfr[f][i]);

    bf16x8 pa[2];
#pragma unroll
    for (int k2 = 0; k2 < 2; ++k2)
      pa[k2] = *reinterpret_cast<const bf16x8*>(&ps[w][lr][k2 * 32 + lg * 8]);
#pragma unroll
    for (int nf = 0; nf < 4; ++nf)
#pragma unroll
      for (int k2 = 0; k2 < 2; ++k2) {
        bf16x8 vb = *reinterpret_cast<const bf16x8*>(&vs[nf * 16 + lr][k2 * 32 + lg * 8]);
        oacc[nf] = MFMA16(pa[k2], vb, oacc[nf]);
      }
  }

  const int growb = b * 2048 + q0 + w * 16 + lg * 4;  // global row of i=0
#pragma unroll
  for (int nf = 0; nf < 4; ++nf) {
    const int d = nf * 16 + lr;
#pragma unroll
    for (int i = 0; i < 4; ++i)
      Op[(c * 16384 + growb + i) * 64 + d] = oacc[nf][i];
  }
  if (lr == 0) {
#pragma unroll
    for (int i = 0; i < 4; ++i) {
      mp[c * 16384 + growb + i] = m_i[i];
      lp[c * 16384 + growb + i] = l_i[i];
    }
  }
}

// ---------------------------------------------------------------------------
// Kernel 3: merge the 4 kv-chunk partials. out = sum(w_c*O_c)/sum(w_c*l_c).
// ---------------------------------------------------------------------------
__global__ __launch_bounds__(256) void merge_kernel(
    const float* __restrict__ Op, const float* __restrict__ mp,
    const float* __restrict__ lp, float* __restrict__ out) {
  const int t = blockIdx.x * 256 + threadIdx.x;  // 0..262143
  const int row = t >> 4;                        // b*2048 + q
  const int cc = (t & 15) * 4;
  float mv[4], lv[4];
#pragma unroll
  for (int c = 0; c < 4; ++c) {
    mv[c] = mp[c * 16384 + row];
    lv[c] = lp[c * 16384 + row];
  }
  const float M = fmaxf(fmaxf(mv[0], mv[1]), fmaxf(mv[2], mv[3]));
  float L = 0.0f;
  f32x4 o = {};
#pragma unroll
  for (int c = 0; c < 4; ++c) {
    const float wc = __expf(mv[c] - M);
    L += wc * lv[c];
    f32x4 oc = *reinterpret_cast<const f32x4*>(&Op[(c * 16384 + row) * 64 + cc]);
    o += oc * wc;
  }
  const float inv = 1.0f / L;
  *reinterpret_cast<f32x4*>(&out[row * 64 + cc]) = o * inv;
}

// ---------------------------------------------------------------------------
extern "C" void kernel_launch(void* const* d_in, const int* in_sizes, int n_in,
                              void* d_out, int out_size, void* d_ws, size_t ws_size,
                              hipStream_t stream) {
  const float* x  = (const float*)d_in[0];
  const int* mask = (const int*)d_in[1];
  const float* Wq = (const float*)d_in[2];
  const float* bq = (const float*)d_in[3];
  const float* Wk = (const float*)d_in[4];
  const float* bk = (const float*)d_in[5];
  const float* Wv = (const float*)d_in[6];
  const float* bv = (const float*)d_in[7];
  float* out = (float*)d_out;

  unsigned short* Wt = (unsigned short*)d_ws;   // [192][1024] swizzled bf16
  unsigned short* Qw = Wt + 192 * 1024;         // [8][2048][64]
  unsigned short* Kw = Qw + 16384 * 64;         // [8][2048][64]
  unsigned short* Vt = Kw + 16384 * 64;         // [8][64][2048]
  float* Op = (float*)(Vt + 16384 * 64);        // [4][16384][64]
  float* mp = Op + 4 * 16384 * 64;              // [4][16384]
  float* lp = mp + 4 * 16384;                   // [4][16384]

  hipLaunchKernelGGL(wt_kernel, dim3(192), dim3(128), 0, stream, Wq, Wk, Wv, Wt);
  hipLaunchKernelGGL(qkv_kernel, dim3(512), dim3(512), 0, stream,
                     x, Wt, bq, bk, bv, Qw, Kw, Vt);
  hipLaunchKernelGGL(attn_kernel, dim3(32, 8, 4), dim3(256), 0, stream,
                     Qw, Kw, Vt, mask, Op, mp, lp);
  hipLaunchKernelGGL(merge_kernel, dim3(1024), dim3(256), 0, stream,
                     Op, mp, lp, out);
}